// Round 6
// baseline (42.919 us; speedup 1.0000x reference)
//
#include <hip/hip_runtime.h>

#define FLT_MAX_ 3.402823466e+38f

constexpr int PARTS = 8;             // waves per workgroup
constexpr int CB    = 4;             // channels per wave for the STATS passes (32/8)
constexpr int HW    = 9216;          // 96*96

using bf16x8 = __attribute__((ext_vector_type(8))) short;
using f32x4  = __attribute__((ext_vector_type(4))) float;
using u32x4  = __attribute__((ext_vector_type(4))) unsigned int;

// packed bf16 pair via HW cvt (RNE): r[15:0]=bf16(a), r[31:16]=bf16(b)
__device__ inline unsigned cvtpk_bf16(float a, float b) {
    unsigned r;
    asm("v_cvt_pk_bf16_f32 %0, %1, %2" : "=v"(r) : "v"(a), "v"(b));
    return r;
}
// exact split: p = hi + lo with hi = bf16(p) (RNE); packed hi & lo for a pair
__device__ inline void split2(float p0, float p1, unsigned &h, unsigned &l) {
    h = cvtpk_bf16(p0, p1);
    const float h0 = __builtin_bit_cast(float, h << 16);
    const float h1 = __builtin_bit_cast(float, h & 0xFFFF0000u);
    l = cvtpk_bf16(p0 - h0, p1 - h1);
}

// ---- prep: phi_w [j=ch*9+tap][64k] fp32 -> ws fragments, K reordered j'' = tap*32+ch ----
// ws layout (uint4 units): [mat 2(hi,lo)][tap 9][n 4][lane 64], frag = 8 bf16 = 1 uint4
__global__ __launch_bounds__(256)
void prep_w(const float* __restrict__ phi_w, u32x4* __restrict__ wsq) {
    const int kb   = blockIdx.x;          // tap 0..8
    const int n    = threadIdx.x >> 6;    // 0..3
    const int lane = threadIdx.x & 63;
    const int lg   = lane >> 4, kk = lane & 15;
    float p[8];
    #pragma unroll
    for (int jj = 0; jj < 8; ++jj) {
        const int ch = lg * 8 + jj;
        p[jj] = phi_w[(ch * 9 + kb) * 64 + n * 16 + kk];
    }
    unsigned h0,h1,h2,h3, l0,l1,l2,l3;
    split2(p[0],p[1],h0,l0); split2(p[2],p[3],h1,l1);
    split2(p[4],p[5],h2,l2); split2(p[6],p[7],h3,l3);
    wsq[(kb * 4 + n) * 64 + lane]        = u32x4{h0,h1,h2,h3};
    wsq[2304 + (kb * 4 + n) * 64 + lane] = u32x4{l0,l1,l2,l3};
}

__global__ __launch_bounds__(512)
void sac_fused(const float* __restrict__ x,
               const float* __restrict__ fc1_w, const float* __restrict__ fc1_b,
               const float* __restrict__ alpha_w, const float* __restrict__ alpha_b,
               const float* __restrict__ phi_b,
               const float* __restrict__ bn_g, const float* __restrict__ bn_b,
               const float* __restrict__ bn_m, const float* __restrict__ bn_v,
               const u32x4* __restrict__ wsq,
               float* __restrict__ out)
{
    __shared__ float    h_lds[64 * 65];     // 16640 B [pos][k] pad 65: (lane+k)%32 conflict-free
    __shared__ float    red7[7 * 512];      // 14336 B {s1,mn,mx,s2,s3,s4,phib}; [0..127] reused as redP
    __shared__ unsigned cnts[16 * 64];      //  4096 B [bin][pos]
                                            // total 35072 B -> 4 WGs/CU by LDS

    const int tid  = threadIdx.x;
    const int lane = tid & 63;
    const int w    = __builtin_amdgcn_readfirstlane(tid >> 6);   // wave-uniform
    const int g    = blockIdx.x;
    const int b    = g / 144;
    const int rem  = g - b * 144;
    const int ty   = rem / 3;               // 0..47  (row pair)
    const int tx   = rem - ty * 3;          // 0..2   (32-col third)
    const int y0   = ty * 2, x0 = tx * 32;
    const int r    = lane >> 5;             // row within pair (0..1)
    const int c    = lane & 31;             // col within third (0..31)
    const int row  = y0 + r, col = x0 + c;

    cnts[tid] = 0u;
    cnts[tid + 512] = 0u;

    const float* __restrict__ xb = x + (size_t)b * 32 * HW;
    const float* __restrict__ xw = xb + (size_t)(w * CB) * HW;   // this wave's 4 channels

    // ------------- pass A: power sums s1..s4, min, max, phi_b.p (taps from L1/L2) -------------
    float s1 = 0.f, s2 = 0.f, s3 = 0.f, s4 = 0.f;
    float mn = FLT_MAX_, mx = -FLT_MAX_, projp = 0.f;
    #pragma unroll
    for (int dy = 0; dy < 3; ++dy) {
        const int y   = row + dy - 1;
        const bool yok = (unsigned)y < 96u;
        #pragma unroll
        for (int dx = 0; dx < 3; ++dx) {
            const int xx2 = col + dx - 1;
            const bool ok = yok && ((unsigned)xx2 < 96u);
            const int off = y * 96 + xx2;
            #pragma unroll
            for (int cc = 0; cc < CB; ++cc) {
                const float p  = ok ? xw[cc * HW + off] : 0.f;
                const float pp = p * p;
                s1 += p;
                s2 = fmaf(p, p, s2);
                s3 = fmaf(pp, p, s3);
                s4 = fmaf(pp, pp, s4);
                mn = fminf(mn, p);
                mx = fmaxf(mx, p);
                const int j = (w * CB + cc) * 9 + dy * 3 + dx;   // uniform -> s_load
                projp = fmaf(p, phi_b[j], projp);
            }
        }
    }
    red7[tid]         = s1;
    red7[512 + tid]   = mn;
    red7[1024 + tid]  = mx;
    red7[1536 + tid]  = s2;
    red7[2048 + tid]  = s3;
    red7[2560 + tid]  = s4;
    red7[3072 + tid]  = projp;                       // phi_b . p partials
    __syncthreads();                                 // B1: red7 + cnts-zero ready

    float ts1 = 0.f, tmn = FLT_MAX_, tmx = -FLT_MAX_;
    #pragma unroll
    for (int rr = 0; rr < PARTS; ++rr) {
        ts1 += red7[rr * 64 + lane];
        tmn = fminf(tmn, red7[512 + rr * 64 + lane]);
        tmx = fmaxf(tmx, red7[1024 + rr * 64 + lane]);
    }
    const float mu   = ts1 * (1.0f / 288.0f);
    const float rng  = (tmx - tmn) + 1e-6f;          // exact: min/max order-free
    const float invr = 1.0f / rng;                   // one IEEE div per position

    // ---------------- pass B: histogram (reload taps, L1-hot) ----------------
    #pragma unroll
    for (int dy = 0; dy < 3; ++dy) {
        const int y   = row + dy - 1;
        const bool yok = (unsigned)y < 96u;
        #pragma unroll
        for (int dx = 0; dx < 3; ++dx) {
            const int xx2 = col + dx - 1;
            const bool ok = yok && ((unsigned)xx2 < 96u);
            const int off = y * 96 + xx2;
            #pragma unroll
            for (int cc = 0; cc < CB; ++cc) {
                const float p  = ok ? xw[cc * HW + off] : 0.f;
                const float pn = (p - tmn) * invr;
                int bi = (int)(pn * 15.0f);
                bi = bi < 0 ? 0 : (bi > 15 ? 15 : bi);
                atomicAdd(&cnts[bi * 64 + lane], 1u);
            }
        }
    }
    __syncthreads();                                 // B2: cnts final

    // ------- finalize stats (ALL waves, redundant = parallel) + h k-slice -> LDS -------
    {
        float u2 = 0.f, u3 = 0.f, u4 = 0.f;
        #pragma unroll
        for (int rr = 0; rr < PARTS; ++rr) {
            u2 += red7[1536 + rr * 64 + lane];
            u3 += red7[2048 + rr * 64 + lane];
            u4 += red7[2560 + rr * 64 + lane];
        }
        const float e2  = u2 * (1.0f / 288.0f);
        const float e3  = u3 * (1.0f / 288.0f);
        const float e4  = u4 * (1.0f / 288.0f);
        const float mu2 = mu * mu;
        const float var = fmaxf(e2 - mu2, 0.f);
        const float m3  = e3 - 3.f * mu * e2 + 2.f * mu * mu2;
        const float m4  = e4 - 4.f * mu * e3 + 6.f * mu2 * e2 - 3.f * mu2 * mu2;
        const float sig = sqrtf(var + 1e-6f);
        const float inv = 1.0f / (sig + 1e-6f);
        const float inv2 = inv * inv;
        const float gam = m3 * (inv2 * inv);
        const float kap = m4 * (inv2 * inv2) - 3.0f;
        float ent = 0.f;
        #pragma unroll
        for (int bi = 0; bi < 16; ++bi) {
            const float prob = (float)cnts[bi * 64 + lane] * (1.0f / 288.0f);
            ent -= prob * __logf(prob + 1e-9f);
        }
        // h for OWN position (lane), k-slice w*8..w*8+7  (fc1 rows: wave-uniform s_loads)
        #pragma unroll
        for (int kk = 0; kk < 8; ++kk) {
            const int k = w * 8 + kk;
            float acc = fc1_b[k];
            acc = fmaf(mu,  fc1_w[k * 5 + 0], acc);
            acc = fmaf(sig, fc1_w[k * 5 + 1], acc);
            acc = fmaf(gam, fc1_w[k * 5 + 2], acc);
            acc = fmaf(kap, fc1_w[k * 5 + 3], acc);
            acc = fmaf(ent, fc1_w[k * 5 + 4], acc);
            h_lds[lane * 65 + k] = fmaxf(acc, 0.f);
        }
    }
    __syncthreads();                                 // B3: h ready

    // ======== t-GEMM via MFMA: T[64 pos][64 k] = P[64x288] . W[288x64] ========
    // K permuted j'' = tap*32 + ch (A & B identically). Wave w: m = w>>1, n = (w&1)*2+{0,1}.
    // bf16 triple-split: T = (Ph+Pl).(Wh+Wl), 4 products, fp32 accum -> ~2^-15 rel.
    {
        const int m    = w >> 1;
        const int np   = (w & 1) * 2;
        const int lg   = lane >> 4;
        const int posa = m * 16 + (lane & 15);
        const int ra   = posa >> 5, ca = posa & 31;
        const int rowa = y0 + ra, cola = x0 + ca;
        const float* __restrict__ xg8 = xb + (size_t)(lg * 8) * HW;  // this lane-group's 8 ch

        f32x4 acc0 = {0.f, 0.f, 0.f, 0.f};
        f32x4 acc1 = {0.f, 0.f, 0.f, 0.f};

        #pragma unroll
        for (int tap = 0; tap < 9; ++tap) {
            const int dy = tap / 3, dx = tap % 3;        // compile-time
            const u32x4 bh0 = wsq[(tap * 4 + np) * 64 + lane];
            const u32x4 bh1 = wsq[(tap * 4 + np + 1) * 64 + lane];
            const u32x4 bl0 = wsq[2304 + (tap * 4 + np) * 64 + lane];
            const u32x4 bl1 = wsq[2304 + (tap * 4 + np + 1) * 64 + lane];

            const int ya = rowa + dy - 1, xa = cola + dx - 1;
            const bool ok = ((unsigned)ya < 96u) && ((unsigned)xa < 96u);
            const int off = ya * 96 + xa;
            const float p0 = ok ? xg8[0 * HW + off] : 0.f;
            const float p1 = ok ? xg8[1 * HW + off] : 0.f;
            const float p2 = ok ? xg8[2 * HW + off] : 0.f;
            const float p3 = ok ? xg8[3 * HW + off] : 0.f;
            const float p4 = ok ? xg8[4 * HW + off] : 0.f;
            const float p5 = ok ? xg8[5 * HW + off] : 0.f;
            const float p6 = ok ? xg8[6 * HW + off] : 0.f;
            const float p7 = ok ? xg8[7 * HW + off] : 0.f;
            unsigned ah0,ah1,ah2,ah3, al0,al1,al2,al3;
            split2(p0,p1,ah0,al0); split2(p2,p3,ah1,al1);
            split2(p4,p5,ah2,al2); split2(p6,p7,ah3,al3);
            const bf16x8 Ah  = __builtin_bit_cast(bf16x8, u32x4{ah0,ah1,ah2,ah3});
            const bf16x8 Al  = __builtin_bit_cast(bf16x8, u32x4{al0,al1,al2,al3});
            const bf16x8 Bh0 = __builtin_bit_cast(bf16x8, bh0);
            const bf16x8 Bl0 = __builtin_bit_cast(bf16x8, bl0);
            const bf16x8 Bh1 = __builtin_bit_cast(bf16x8, bh1);
            const bf16x8 Bl1 = __builtin_bit_cast(bf16x8, bl1);

            acc0 = __builtin_amdgcn_mfma_f32_16x16x32_bf16(Ah, Bh0, acc0, 0, 0, 0);
            acc0 = __builtin_amdgcn_mfma_f32_16x16x32_bf16(Ah, Bl0, acc0, 0, 0, 0);
            acc0 = __builtin_amdgcn_mfma_f32_16x16x32_bf16(Al, Bh0, acc0, 0, 0, 0);
            acc0 = __builtin_amdgcn_mfma_f32_16x16x32_bf16(Al, Bl0, acc0, 0, 0, 0);
            acc1 = __builtin_amdgcn_mfma_f32_16x16x32_bf16(Ah, Bh1, acc1, 0, 0, 0);
            acc1 = __builtin_amdgcn_mfma_f32_16x16x32_bf16(Ah, Bl1, acc1, 0, 0, 0);
            acc1 = __builtin_amdgcn_mfma_f32_16x16x32_bf16(Al, Bh1, acc1, 0, 0, 0);
            acc1 = __builtin_amdgcn_mfma_f32_16x16x32_bf16(Al, Bl1, acc1, 0, 0, 0);
        }

        // proj partials: C/D layout col = lane&15 (k), row = lg*4 + q (pos)
        const int k0 = np * 16 + (lane & 15);
        const int k1 = k0 + 16;
        float pr0, pr1, pr2, pr3;
        {
            const int pb = (m * 16 + lg * 4) * 65;
            pr0 = acc0[0] * h_lds[pb + 0 * 65 + k0] + acc1[0] * h_lds[pb + 0 * 65 + k1];
            pr1 = acc0[1] * h_lds[pb + 1 * 65 + k0] + acc1[1] * h_lds[pb + 1 * 65 + k1];
            pr2 = acc0[2] * h_lds[pb + 2 * 65 + k0] + acc1[2] * h_lds[pb + 2 * 65 + k1];
            pr3 = acc0[3] * h_lds[pb + 3 * 65 + k0] + acc1[3] * h_lds[pb + 3 * 65 + k1];
        }
        #pragma unroll
        for (int msk = 1; msk < 16; msk <<= 1) {
            pr0 += __shfl_xor(pr0, msk);
            pr1 += __shfl_xor(pr1, msk);
            pr2 += __shfl_xor(pr2, msk);
            pr3 += __shfl_xor(pr3, msk);
        }
        if ((lane & 15) == 0) {                      // redP aliases red7[0..127] (s1 dead)
            const int pb = m * 16 + lg * 4;
            red7[(pb + 0) * 2 + (w & 1)] = pr0;
            red7[(pb + 1) * 2 + (w & 1)] = pr1;
            red7[(pb + 2) * 2 + (w & 1)] = pr2;
            red7[(pb + 3) * 2 + (w & 1)] = pr3;
        }
    }
    __syncthreads();                                 // B4: redP ready

    float proj = red7[2 * lane] + red7[2 * lane + 1];
    #pragma unroll
    for (int rr = 0; rr < PARTS; ++rr)
        proj += red7[3072 + rr * 64 + lane];         // phi_b . p

    // ---------------- alpha (8 channels per wave) + BN + SiLU ----------------
    float acc8[8];
    #pragma unroll
    for (int cj = 0; cj < 8; ++cj) acc8[cj] = 0.f;
    #pragma unroll 16
    for (int k = 0; k < 64; ++k) {
        const float hk = h_lds[lane * 65 + k];
        #pragma unroll
        for (int cj = 0; cj < 8; ++cj)
            acc8[cj] = fmaf(hk, alpha_w[(w * 8 + cj) * 64 + k], acc8[cj]); // s_load
    }
    #pragma unroll
    for (int cj = 0; cj < 8; ++cj) {
        const int ch     = w * 8 + cj;
        const float a    = acc8[cj] + alpha_b[ch];
        const float o    = a * proj;
        const float binv = bn_g[ch] * rsqrtf(bn_v[ch] + 1e-5f);
        const float yv   = (o - bn_m[ch]) * binv + bn_b[ch];
        const float sv   = __fdividef(yv, 1.0f + __expf(-yv));   // silu
        out[((size_t)(b * 64 + ch)) * HW + (size_t)(row * 96 + col)] = sv;
    }
}

extern "C" void kernel_launch(void* const* d_in, const int* in_sizes, int n_in,
                              void* d_out, int out_size, void* d_ws, size_t ws_size,
                              hipStream_t stream) {
    const float* x   = (const float*)d_in[0];
    const float* f1w = (const float*)d_in[1];
    const float* f1b = (const float*)d_in[2];
    const float* aw  = (const float*)d_in[3];
    const float* ab  = (const float*)d_in[4];
    const float* pw  = (const float*)d_in[5];
    const float* pb  = (const float*)d_in[6];
    const float* bg  = (const float*)d_in[7];
    const float* bb  = (const float*)d_in[8];
    const float* bm  = (const float*)d_in[9];
    const float* bv  = (const float*)d_in[10];

    u32x4* wsq = (u32x4*)d_ws;   // 73728 B used

    prep_w<<<dim3(9), dim3(256), 0, stream>>>(pw, wsq);
    sac_fused<<<dim3(576), dim3(512), 0, stream>>>(
        x, f1w, f1b, aw, ab, pb, bg, bb, bm, bv, wsq, (float*)d_out);
}

// Round 7
// 34.233 us; speedup vs baseline: 1.2537x; 1.2537x over previous
//
#include <hip/hip_runtime.h>

#define FLT_MAX_ 3.402823466e+38f

constexpr int PARTS = 8;             // waves per workgroup
constexpr int CB    = 4;             // channels per wave for the STATS pass (32/8)
constexpr int HW    = 9216;          // 96*96
constexpr int AOFF  = 4608;          // u32x4 offset of alpha frags in ws (phi uses 0..4607)

using bf16x8 = __attribute__((ext_vector_type(8))) short;
using f32x4  = __attribute__((ext_vector_type(4))) float;
using u32x4  = __attribute__((ext_vector_type(4))) unsigned int;

// packed bf16 pair via HW cvt (RNE): r[15:0]=bf16(a), r[31:16]=bf16(b)
__device__ inline unsigned cvtpk_bf16(float a, float b) {
    unsigned r;
    asm("v_cvt_pk_bf16_f32 %0, %1, %2" : "=v"(r) : "v"(a), "v"(b));
    return r;
}
// exact split: p = hi + lo with hi = bf16(p) (RNE); packed hi & lo for a pair
__device__ inline void split2(float p0, float p1, unsigned &h, unsigned &l) {
    h = cvtpk_bf16(p0, p1);
    const float h0 = __builtin_bit_cast(float, h << 16);
    const float h1 = __builtin_bit_cast(float, h & 0xFFFF0000u);
    l = cvtpk_bf16(p0 - h0, p1 - h1);
}

// ---- prep: weights -> MFMA B-fragments (hi/lo bf16), L2-resident in ws ----
// phi: [mat 2][tap 9][n 4][lane 64] u32x4, K reordered j'' = tap*32+ch
// alpha (at AOFF): [mat 2][kblk 2][n 4][lane 64] u32x4, B[k][c] = alpha_w[c][k]
__global__ __launch_bounds__(256)
void prep_w(const float* __restrict__ phi_w, const float* __restrict__ alpha_w,
            u32x4* __restrict__ wsq) {
    const int kb   = blockIdx.x;          // 0..8 = phi tap, 9 = alpha
    const int n    = threadIdx.x >> 6;    // 0..3
    const int lane = threadIdx.x & 63;
    const int lg   = lane >> 4, kk = lane & 15;
    if (kb < 9) {
        float p[8];
        #pragma unroll
        for (int jj = 0; jj < 8; ++jj) {
            const int ch = lg * 8 + jj;
            p[jj] = phi_w[(ch * 9 + kb) * 64 + n * 16 + kk];
        }
        unsigned h0,h1,h2,h3, l0,l1,l2,l3;
        split2(p[0],p[1],h0,l0); split2(p[2],p[3],h1,l1);
        split2(p[4],p[5],h2,l2); split2(p[6],p[7],h3,l3);
        wsq[(kb * 4 + n) * 64 + lane]        = u32x4{h0,h1,h2,h3};
        wsq[2304 + (kb * 4 + n) * 64 + lane] = u32x4{l0,l1,l2,l3};
    } else {
        #pragma unroll
        for (int kblk = 0; kblk < 2; ++kblk) {
            float p[8];
            #pragma unroll
            for (int jj = 0; jj < 8; ++jj) {
                const int k = kblk * 32 + lg * 8 + jj;
                p[jj] = alpha_w[(n * 16 + kk) * 64 + k];   // B[k][c] = alpha_w[c][k]
            }
            unsigned h0,h1,h2,h3, l0,l1,l2,l3;
            split2(p[0],p[1],h0,l0); split2(p[2],p[3],h1,l1);
            split2(p[4],p[5],h2,l2); split2(p[6],p[7],h3,l3);
            wsq[AOFF + (kblk * 4 + n) * 64 + lane]       = u32x4{h0,h1,h2,h3};
            wsq[AOFF + 512 + (kblk * 4 + n) * 64 + lane] = u32x4{l0,l1,l2,l3};
        }
    }
}

__global__ __launch_bounds__(512, 3)
void sac_fused(const float* __restrict__ x,
               const float* __restrict__ fc1_w, const float* __restrict__ fc1_b,
               const float* __restrict__ alpha_b,
               const float* __restrict__ phi_b,
               const float* __restrict__ bn_g, const float* __restrict__ bn_b,
               const float* __restrict__ bn_m, const float* __restrict__ bn_v,
               const u32x4* __restrict__ wsq,
               float* __restrict__ out)
{
    __shared__ float    h_lds[64 * 65];     // 16640 B [pos][k] pad 65
    __shared__ float    red7[7 * 512];      // 14336 B {s1,mn,mx,s2,s3,s4,phib}; [0..127] -> redP
    __shared__ unsigned cnts[16 * 64];      //  4096 B [bin][pos]
                                            // total 35072 B -> 4 WGs/CU by LDS

    const int tid  = threadIdx.x;
    const int lane = tid & 63;
    const int w    = __builtin_amdgcn_readfirstlane(tid >> 6);   // wave-uniform
    const int g    = blockIdx.x;
    const int b    = g / 144;
    const int rem  = g - b * 144;
    const int ty   = rem / 3;               // 0..47  (row pair)
    const int tx   = rem - ty * 3;          // 0..2   (32-col third)
    const int y0   = ty * 2, x0 = tx * 32;
    const int r    = lane >> 5;             // row within pair (0..1)
    const int c    = lane & 31;             // col within third (0..31)
    const int row  = y0 + r, col = x0 + c;

    cnts[tid] = 0u;
    cnts[tid + 512] = 0u;

    const float* __restrict__ xb = x + (size_t)b * 32 * HW;
    const float* __restrict__ xw = xb + (size_t)(w * CB) * HW;   // this wave's 4 channels

    // ------------- pass A: taps -> pv[36] registers + power sums + min/max + phi_b.p -------------
    float pv[36];
    float s1 = 0.f, s2 = 0.f, s3 = 0.f, s4 = 0.f;
    float mn = FLT_MAX_, mx = -FLT_MAX_, projp = 0.f;
    #pragma unroll
    for (int dy = 0; dy < 3; ++dy) {
        const int y    = row + dy - 1;
        const bool yok = (unsigned)y < 96u;
        #pragma unroll
        for (int dx = 0; dx < 3; ++dx) {
            const int xx2 = col + dx - 1;
            const bool ok = yok && ((unsigned)xx2 < 96u);
            const int off = y * 96 + xx2;
            #pragma unroll
            for (int cc = 0; cc < CB; ++cc) {
                const float p = ok ? xw[cc * HW + off] : 0.f;
                pv[(dy * 3 + dx) * 4 + cc] = p;
                const float pp = p * p;
                s1 += p;
                s2 = fmaf(p, p, s2);
                s3 = fmaf(pp, p, s3);
                s4 = fmaf(pp, pp, s4);
                mn = fminf(mn, p);
                mx = fmaxf(mx, p);
                const int j = (w * CB + cc) * 9 + dy * 3 + dx;   // uniform -> s_load
                projp = fmaf(p, phi_b[j], projp);
            }
        }
    }
    red7[tid]         = s1;
    red7[512 + tid]   = mn;
    red7[1024 + tid]  = mx;
    red7[1536 + tid]  = s2;
    red7[2048 + tid]  = s3;
    red7[2560 + tid]  = s4;
    red7[3072 + tid]  = projp;                       // phi_b . p partials
    __syncthreads();                                 // B1

    float ts1 = 0.f, tmn = FLT_MAX_, tmx = -FLT_MAX_;
    #pragma unroll
    for (int rr = 0; rr < PARTS; ++rr) {
        ts1 += red7[rr * 64 + lane];
        tmn = fminf(tmn, red7[512 + rr * 64 + lane]);
        tmx = fmaxf(tmx, red7[1024 + rr * 64 + lane]);
    }
    const float mu   = ts1 * (1.0f / 288.0f);
    const float rng  = (tmx - tmn) + 1e-6f;          // exact: min/max order-free
    const float invr = 1.0f / rng;

    // ---------------- histogram from live registers (no reload) ----------------
    #pragma unroll
    for (int i = 0; i < 36; ++i) {
        const float pn = (pv[i] - tmn) * invr;
        int bi = (int)(pn * 15.0f);
        bi = bi < 0 ? 0 : (bi > 15 ? 15 : bi);
        atomicAdd(&cnts[bi * 64 + lane], 1u);
    }
    __syncthreads();                                 // B2: cnts final

    // ------- finalize stats (ALL waves, redundant = parallel) + h k-slice -> LDS -------
    {
        float u2 = 0.f, u3 = 0.f, u4 = 0.f;
        #pragma unroll
        for (int rr = 0; rr < PARTS; ++rr) {
            u2 += red7[1536 + rr * 64 + lane];
            u3 += red7[2048 + rr * 64 + lane];
            u4 += red7[2560 + rr * 64 + lane];
        }
        const float e2  = u2 * (1.0f / 288.0f);
        const float e3  = u3 * (1.0f / 288.0f);
        const float e4  = u4 * (1.0f / 288.0f);
        const float mu2 = mu * mu;
        const float var = fmaxf(e2 - mu2, 0.f);
        const float m3  = e3 - 3.f * mu * e2 + 2.f * mu * mu2;
        const float m4  = e4 - 4.f * mu * e3 + 6.f * mu2 * e2 - 3.f * mu2 * mu2;
        const float sig = sqrtf(var + 1e-6f);
        const float inv = 1.0f / (sig + 1e-6f);
        const float inv2 = inv * inv;
        const float gam = m3 * (inv2 * inv);
        const float kap = m4 * (inv2 * inv2) - 3.0f;
        float ent = 0.f;
        #pragma unroll
        for (int bi = 0; bi < 16; ++bi) {
            const float prob = (float)cnts[bi * 64 + lane] * (1.0f / 288.0f);
            ent -= prob * __logf(prob + 1e-9f);
        }
        #pragma unroll
        for (int kk = 0; kk < 8; ++kk) {
            const int k = w * 8 + kk;
            float acc = fc1_b[k];
            acc = fmaf(mu,  fc1_w[k * 5 + 0], acc);
            acc = fmaf(sig, fc1_w[k * 5 + 1], acc);
            acc = fmaf(gam, fc1_w[k * 5 + 2], acc);
            acc = fmaf(kap, fc1_w[k * 5 + 3], acc);
            acc = fmaf(ent, fc1_w[k * 5 + 4], acc);
            h_lds[lane * 65 + k] = fmaxf(acc, 0.f);
        }
    }
    __syncthreads();                                 // B3: h ready

    const int m    = w >> 1;
    const int np   = (w & 1) * 2;
    const int lg   = lane >> 4;

    // ======== t-GEMM via MFMA (3-product split: AhBh + AhBl + AlBh) ========
    {
        const int posa = m * 16 + (lane & 15);
        const int ra   = posa >> 5, ca = posa & 31;
        const int rowa = y0 + ra, cola = x0 + ca;
        const float* __restrict__ xg8 = xb + (size_t)(lg * 8) * HW;

        f32x4 acc0 = {0.f, 0.f, 0.f, 0.f};
        f32x4 acc1 = {0.f, 0.f, 0.f, 0.f};

        #pragma unroll
        for (int tap = 0; tap < 9; ++tap) {
            const int dy = tap / 3, dx = tap % 3;        // compile-time
            const u32x4 bh0 = wsq[(tap * 4 + np) * 64 + lane];
            const u32x4 bh1 = wsq[(tap * 4 + np + 1) * 64 + lane];
            const u32x4 bl0 = wsq[2304 + (tap * 4 + np) * 64 + lane];
            const u32x4 bl1 = wsq[2304 + (tap * 4 + np + 1) * 64 + lane];

            const int ya = rowa + dy - 1, xa = cola + dx - 1;
            const bool ok = ((unsigned)ya < 96u) && ((unsigned)xa < 96u);
            const int off = ya * 96 + xa;
            const float p0 = ok ? xg8[0 * HW + off] : 0.f;
            const float p1 = ok ? xg8[1 * HW + off] : 0.f;
            const float p2 = ok ? xg8[2 * HW + off] : 0.f;
            const float p3 = ok ? xg8[3 * HW + off] : 0.f;
            const float p4 = ok ? xg8[4 * HW + off] : 0.f;
            const float p5 = ok ? xg8[5 * HW + off] : 0.f;
            const float p6 = ok ? xg8[6 * HW + off] : 0.f;
            const float p7 = ok ? xg8[7 * HW + off] : 0.f;
            unsigned ah0,ah1,ah2,ah3, al0,al1,al2,al3;
            split2(p0,p1,ah0,al0); split2(p2,p3,ah1,al1);
            split2(p4,p5,ah2,al2); split2(p6,p7,ah3,al3);
            const bf16x8 Ah  = __builtin_bit_cast(bf16x8, u32x4{ah0,ah1,ah2,ah3});
            const bf16x8 Al  = __builtin_bit_cast(bf16x8, u32x4{al0,al1,al2,al3});
            const bf16x8 Bh0 = __builtin_bit_cast(bf16x8, bh0);
            const bf16x8 Bl0 = __builtin_bit_cast(bf16x8, bl0);
            const bf16x8 Bh1 = __builtin_bit_cast(bf16x8, bh1);
            const bf16x8 Bl1 = __builtin_bit_cast(bf16x8, bl1);

            acc0 = __builtin_amdgcn_mfma_f32_16x16x32_bf16(Ah, Bh0, acc0, 0, 0, 0);
            acc0 = __builtin_amdgcn_mfma_f32_16x16x32_bf16(Ah, Bl0, acc0, 0, 0, 0);
            acc0 = __builtin_amdgcn_mfma_f32_16x16x32_bf16(Al, Bh0, acc0, 0, 0, 0);
            acc1 = __builtin_amdgcn_mfma_f32_16x16x32_bf16(Ah, Bh1, acc1, 0, 0, 0);
            acc1 = __builtin_amdgcn_mfma_f32_16x16x32_bf16(Ah, Bl1, acc1, 0, 0, 0);
            acc1 = __builtin_amdgcn_mfma_f32_16x16x32_bf16(Al, Bh1, acc1, 0, 0, 0);
        }

        // proj partials: C/D layout col = lane&15 (k), row = lg*4 + q (pos)
        const int k0 = np * 16 + (lane & 15);
        const int k1 = k0 + 16;
        float pr0, pr1, pr2, pr3;
        {
            const int pb = (m * 16 + lg * 4) * 65;
            pr0 = acc0[0] * h_lds[pb + 0 * 65 + k0] + acc1[0] * h_lds[pb + 0 * 65 + k1];
            pr1 = acc0[1] * h_lds[pb + 1 * 65 + k0] + acc1[1] * h_lds[pb + 1 * 65 + k1];
            pr2 = acc0[2] * h_lds[pb + 2 * 65 + k0] + acc1[2] * h_lds[pb + 2 * 65 + k1];
            pr3 = acc0[3] * h_lds[pb + 3 * 65 + k0] + acc1[3] * h_lds[pb + 3 * 65 + k1];
        }
        #pragma unroll
        for (int msk = 1; msk < 16; msk <<= 1) {
            pr0 += __shfl_xor(pr0, msk);
            pr1 += __shfl_xor(pr1, msk);
            pr2 += __shfl_xor(pr2, msk);
            pr3 += __shfl_xor(pr3, msk);
        }
        if ((lane & 15) == 0) {                      // redP aliases red7[0..127] (s1 dead)
            const int pb = m * 16 + lg * 4;
            red7[(pb + 0) * 2 + (w & 1)] = pr0;
            red7[(pb + 1) * 2 + (w & 1)] = pr1;
            red7[(pb + 2) * 2 + (w & 1)] = pr2;
            red7[(pb + 3) * 2 + (w & 1)] = pr3;
        }
    }
    __syncthreads();                                 // B4: redP ready

    // ---- proj for this lane's 4 output positions (pos = m*16 + lg*4 + q) ----
    const int pb4 = m * 16 + lg * 4;
    float pj0, pj1, pj2, pj3;
    {
        const f32x4 rp0 = *(const f32x4*)&red7[2 * pb4];
        const f32x4 rp1 = *(const f32x4*)&red7[2 * pb4 + 4];
        pj0 = rp0[0] + rp0[1];
        pj1 = rp0[2] + rp0[3];
        pj2 = rp1[0] + rp1[1];
        pj3 = rp1[2] + rp1[3];
        #pragma unroll
        for (int rr = 0; rr < PARTS; ++rr) {
            const f32x4 ph = *(const f32x4*)&red7[3072 + rr * 64 + pb4];
            pj0 += ph[0]; pj1 += ph[1]; pj2 += ph[2]; pj3 += ph[3];
        }
    }

    // ======== alpha via MFMA: A = h[64 pos][64 k], B = alpha frags ========
    f32x4 ac0 = {0.f, 0.f, 0.f, 0.f};
    f32x4 ac1 = {0.f, 0.f, 0.f, 0.f};
    #pragma unroll
    for (int kblk = 0; kblk < 2; ++kblk) {
        const float* hp = &h_lds[(m * 16 + (lane & 15)) * 65 + kblk * 32 + lg * 8];
        const float h0 = hp[0], h1 = hp[1], h2 = hp[2], h3 = hp[3];
        const float h4 = hp[4], h5 = hp[5], h6 = hp[6], h7 = hp[7];
        unsigned ah0,ah1,ah2,ah3, al0,al1,al2,al3;
        split2(h0,h1,ah0,al0); split2(h2,h3,ah1,al1);
        split2(h4,h5,ah2,al2); split2(h6,h7,ah3,al3);
        const bf16x8 Ah = __builtin_bit_cast(bf16x8, u32x4{ah0,ah1,ah2,ah3});
        const bf16x8 Al = __builtin_bit_cast(bf16x8, u32x4{al0,al1,al2,al3});
        const u32x4 bh0 = wsq[AOFF + (kblk * 4 + np) * 64 + lane];
        const u32x4 bh1 = wsq[AOFF + (kblk * 4 + np + 1) * 64 + lane];
        const u32x4 bl0 = wsq[AOFF + 512 + (kblk * 4 + np) * 64 + lane];
        const u32x4 bl1 = wsq[AOFF + 512 + (kblk * 4 + np + 1) * 64 + lane];
        const bf16x8 Bh0 = __builtin_bit_cast(bf16x8, bh0);
        const bf16x8 Bl0 = __builtin_bit_cast(bf16x8, bl0);
        const bf16x8 Bh1 = __builtin_bit_cast(bf16x8, bh1);
        const bf16x8 Bl1 = __builtin_bit_cast(bf16x8, bl1);
        ac0 = __builtin_amdgcn_mfma_f32_16x16x32_bf16(Ah, Bh0, ac0, 0, 0, 0);
        ac0 = __builtin_amdgcn_mfma_f32_16x16x32_bf16(Ah, Bl0, ac0, 0, 0, 0);
        ac0 = __builtin_amdgcn_mfma_f32_16x16x32_bf16(Al, Bh0, ac0, 0, 0, 0);
        ac1 = __builtin_amdgcn_mfma_f32_16x16x32_bf16(Ah, Bh1, ac1, 0, 0, 0);
        ac1 = __builtin_amdgcn_mfma_f32_16x16x32_bf16(Ah, Bl1, ac1, 0, 0, 0);
        ac1 = __builtin_amdgcn_mfma_f32_16x16x32_bf16(Al, Bh1, ac1, 0, 0, 0);
    }

    // ---- epilogue: alpha + BN + SiLU, 2 channels x 4 consecutive positions ----
    // C/D: row = pos = m*16 + lg*4 + q, col c = n*16 + (lane&15)
    const int c0 = np * 16 + (lane & 15);
    const int r2 = m >> 1;
    const size_t obase = (size_t)(b * 64) * HW
                       + (size_t)(y0 + r2) * 96 + x0 + (m & 1) * 16 + lg * 4;
    {
        const int ch     = c0;
        const float ab_  = alpha_b[ch];
        const float binv = bn_g[ch] * rsqrtf(bn_v[ch] + 1e-5f);
        const float bm_  = bn_m[ch], bb_ = bn_b[ch];
        f32x4 sv;
        {
            const float a0 = ac0[0] + ab_, a1 = ac0[1] + ab_;
            const float a2 = ac0[2] + ab_, a3 = ac0[3] + ab_;
            const float o0 = a0 * pj0, o1 = a1 * pj1, o2 = a2 * pj2, o3 = a3 * pj3;
            const float y0v = (o0 - bm_) * binv + bb_;
            const float y1v = (o1 - bm_) * binv + bb_;
            const float y2v = (o2 - bm_) * binv + bb_;
            const float y3v = (o3 - bm_) * binv + bb_;
            sv[0] = __fdividef(y0v, 1.0f + __expf(-y0v));
            sv[1] = __fdividef(y1v, 1.0f + __expf(-y1v));
            sv[2] = __fdividef(y2v, 1.0f + __expf(-y2v));
            sv[3] = __fdividef(y3v, 1.0f + __expf(-y3v));
        }
        *(f32x4*)&out[obase + (size_t)ch * HW] = sv;
    }
    {
        const int ch     = c0 + 16;
        const float ab_  = alpha_b[ch];
        const float binv = bn_g[ch] * rsqrtf(bn_v[ch] + 1e-5f);
        const float bm_  = bn_m[ch], bb_ = bn_b[ch];
        f32x4 sv;
        {
            const float a0 = ac1[0] + ab_, a1 = ac1[1] + ab_;
            const float a2 = ac1[2] + ab_, a3 = ac1[3] + ab_;
            const float o0 = a0 * pj0, o1 = a1 * pj1, o2 = a2 * pj2, o3 = a3 * pj3;
            const float y0v = (o0 - bm_) * binv + bb_;
            const float y1v = (o1 - bm_) * binv + bb_;
            const float y2v = (o2 - bm_) * binv + bb_;
            const float y3v = (o3 - bm_) * binv + bb_;
            sv[0] = __fdividef(y0v, 1.0f + __expf(-y0v));
            sv[1] = __fdividef(y1v, 1.0f + __expf(-y1v));
            sv[2] = __fdividef(y2v, 1.0f + __expf(-y2v));
            sv[3] = __fdividef(y3v, 1.0f + __expf(-y3v));
        }
        *(f32x4*)&out[obase + (size_t)ch * HW] = sv;
    }
}

extern "C" void kernel_launch(void* const* d_in, const int* in_sizes, int n_in,
                              void* d_out, int out_size, void* d_ws, size_t ws_size,
                              hipStream_t stream) {
    const float* x   = (const float*)d_in[0];
    const float* f1w = (const float*)d_in[1];
    const float* f1b = (const float*)d_in[2];
    const float* aw  = (const float*)d_in[3];
    const float* ab  = (const float*)d_in[4];
    const float* pw  = (const float*)d_in[5];
    const float* pb  = (const float*)d_in[6];
    const float* bg  = (const float*)d_in[7];
    const float* bb  = (const float*)d_in[8];
    const float* bm  = (const float*)d_in[9];
    const float* bv  = (const float*)d_in[10];

    u32x4* wsq = (u32x4*)d_ws;   // 90112 B used

    prep_w<<<dim3(10), dim3(256), 0, stream>>>(pw, aw, wsq);
    sac_fused<<<dim3(576), dim3(512), 0, stream>>>(
        x, f1w, f1b, ab, pb, bg, bb, bm, bv, wsq, (float*)d_out);
}